// Round 5
// baseline (1048.910 us; speedup 1.0000x reference)
//
#include <hip/hip_runtime.h>
#include <math.h>

#define B_ 8
#define N_ 2048
#define D_ 3
#define H_ 256
#define ND_ (N_*D_)     // 6144
#define BN_ (B_*N_)     // 16384
#define NITER_ 14

struct EpsTab { float scl[NITER_], kk[NITER_], hh[NITER_], c1[NITER_], c2[NITER_]; };

// barrier state lives in a device global: immune to ws_size, zeroed by prep each call
__device__ unsigned g_bar[256];

// ---------------- per-batch std (ddof=1) ----------------
__global__ __launch_bounds__(256) void std_kernel(const float* __restrict__ cloud,
                                                  float* __restrict__ stdv) {
  __shared__ float red[256];
  int b = blockIdx.x, tid = threadIdx.x;
  const float* p = cloud + (size_t)b * ND_;
  float s = 0.f;
  for (int i = tid; i < ND_; i += 256) s += p[i];
  red[tid] = s; __syncthreads();
  for (int off = 128; off > 0; off >>= 1) {
    if (tid < off) red[tid] += red[tid + off];
    __syncthreads();
  }
  float mean = red[0] / (float)ND_;
  __syncthreads();
  float ss = 0.f;
  for (int i = tid; i < ND_; i += 256) { float d = p[i] - mean; ss += d * d; }
  red[tid] = ss; __syncthreads();
  for (int off = 128; off > 0; off >>= 1) {
    if (tid < off) red[tid] += red[tid + off];
    __syncthreads();
  }
  if (tid == 0) stdv[b] = sqrtf(red[0] / (float)(ND_ - 1));
}

// ------- pack points as (x,y,z,|p|^2), zero potentials + barrier state -------
__global__ __launch_bounds__(256) void prep_kernel(const float* __restrict__ cloud,
    const float* __restrict__ noise, const float* __restrict__ stdv,
    float4* __restrict__ x0p, float4* __restrict__ np4,
    float* __restrict__ f, float* __restrict__ g) {
  int i = blockIdx.x * 256 + threadIdx.x;
  if (blockIdx.x == 0)
    __hip_atomic_store(&g_bar[threadIdx.x], 0u, __ATOMIC_RELAXED, __HIP_MEMORY_SCOPE_AGENT);
  if (i >= BN_) return;
  int b = i >> 11;
  float sd = stdv[b];
  float cx = cloud[3*i] / sd, cy = cloud[3*i+1] / sd, cz = cloud[3*i+2] / sd;
  x0p[i] = make_float4(cx, cy, cz, cx*cx + cy*cy + cz*cz);
  float ax = noise[3*i], ay = noise[3*i+1], az = noise[3*i+2];
  np4[i] = make_float4(ax, ay, az, ax*ax + ay*ay + az*az);
  f[i] = 0.f; g[i] = 0.f;
}

// per-batch epoch barrier: 32 participating blocks, agent-scope atomics.
__device__ inline void batch_barrier(unsigned* cnt, unsigned* gen, unsigned epoch) {
  __syncthreads();
  if (threadIdx.x == 0) {
    __threadfence();
    unsigned old = __hip_atomic_fetch_add(cnt, 1u, __ATOMIC_ACQ_REL, __HIP_MEMORY_SCOPE_AGENT);
    if (old == 31u) {
      __hip_atomic_store(cnt, 0u, __ATOMIC_RELAXED, __HIP_MEMORY_SCOPE_AGENT);
      __hip_atomic_fetch_add(gen, 1u, __ATOMIC_ACQ_REL, __HIP_MEMORY_SCOPE_AGENT); // orders cnt reset before gen bump
    } else {
      while (__hip_atomic_load(gen, __ATOMIC_ACQUIRE, __HIP_MEMORY_SCOPE_AGENT) < epoch) {
        __builtin_amdgcn_s_sleep(2);
      }
    }
    __threadfence();
  }
  __syncthreads();
}

// ---------------- all 28 Sinkhorn half-iterations in one launch ----------------
// grid = 256 blocks (8 batches x 32 blocks), 256 thr; 1 block/CU -> residency
// structurally guaranteed (no cooperative launch needed).
// Each block: 64 rows (4 grps x 4 waves x 4 rows). Log2-domain lse as in round 2.
// Cross-block f/g traffic uses agent-scope relaxed atomics (L1-bypassing, LLC-
// coherent across XCDs) so correctness doesn't hinge on fence cache-op details.
__global__ __launch_bounds__(256, 2) void sinkhorn_kernel(
    const float4* __restrict__ x0p, const float4* __restrict__ np4,
    float* f, float* g, EpsTab tab) {
  __shared__ float4 sP[N_];   // 32 KB: scaled coords + q
  int tid = threadIdx.x;
  int b   = blockIdx.x >> 5;           // 32 blocks per batch
  int blk = blockIdx.x & 31;           // 64 rows per block
  int base = b * N_;
  unsigned* cnt = &g_bar[b * 16];
  unsigned* gen = &g_bar[128 + b * 16];
  int wave = tid >> 6, lane = tid & 63;
  unsigned epoch = 0;
  for (int kit = 0; kit < NITER_; ++kit) {
    float scl = tab.scl[kit], kk = tab.kk[kit], hh = tab.hh[kit];
    float c1 = tab.c1[kit], c2 = tab.c2[kit];
    for (int half = 0; half < 2; ++half) {
      const float4* outer = half ? x0p : np4;
      const float4* inner = half ? np4 : x0p;
      float*        pin   = half ? f : g;
      float*        pout  = half ? g : f;
      for (int j = tid; j < N_; j += 256) {
        float4 p = inner[base + j];
        float pot = __hip_atomic_load(&pin[base + j], __ATOMIC_RELAXED, __HIP_MEMORY_SCOPE_AGENT);
        float q = fmaf(kk, pot, -hh * p.w);
        sP[j] = make_float4(scl * p.x, scl * p.y, scl * p.z, q);
      }
      __syncthreads();
      for (int grp = 0; grp < 4; ++grp) {
        int r0 = base + (blk << 6) + (grp << 4) + (wave << 2);
        float4 A0 = outer[r0], A1 = outer[r0+1], A2 = outer[r0+2], A3 = outer[r0+3];
        float a0x = scl*A0.x, a0y = scl*A0.y, a0z = scl*A0.z, rc0 = -hh*A0.w;
        float a1x = scl*A1.x, a1y = scl*A1.y, a1z = scl*A1.z, rc1 = -hh*A1.w;
        float a2x = scl*A2.x, a2y = scl*A2.y, a2z = scl*A2.z, rc2 = -hh*A2.w;
        float a3x = scl*A3.x, a3y = scl*A3.y, a3z = scl*A3.z, rc3 = -hh*A3.w;
        float v0[32], v1[32], v2[32], v3[32];
        float m0 = -INFINITY, m1 = -INFINITY, m2 = -INFINITY, m3 = -INFINITY;
#pragma unroll
        for (int jj = 0; jj < 32; ++jj) {
          float4 p = sP[(jj << 6) + lane];
          float t0 = fmaf(p.x, a0x, p.w); t0 = fmaf(p.y, a0y, t0); t0 = fmaf(p.z, a0z, t0);
          v0[jj] = t0; m0 = fmaxf(m0, t0);
          float t1 = fmaf(p.x, a1x, p.w); t1 = fmaf(p.y, a1y, t1); t1 = fmaf(p.z, a1z, t1);
          v1[jj] = t1; m1 = fmaxf(m1, t1);
          float t2 = fmaf(p.x, a2x, p.w); t2 = fmaf(p.y, a2y, t2); t2 = fmaf(p.z, a2z, t2);
          v2[jj] = t2; m2 = fmaxf(m2, t2);
          float t3 = fmaf(p.x, a3x, p.w); t3 = fmaf(p.y, a3y, t3); t3 = fmaf(p.z, a3z, t3);
          v3[jj] = t3; m3 = fmaxf(m3, t3);
        }
#pragma unroll
        for (int off = 32; off >= 1; off >>= 1) {
          m0 = fmaxf(m0, __shfl_xor(m0, off, 64));
          m1 = fmaxf(m1, __shfl_xor(m1, off, 64));
          m2 = fmaxf(m2, __shfl_xor(m2, off, 64));
          m3 = fmaxf(m3, __shfl_xor(m3, off, 64));
        }
        float s0 = 0.f, s1 = 0.f, s2 = 0.f, s3 = 0.f;
#pragma unroll
        for (int jj = 0; jj < 32; ++jj) {
          s0 += __builtin_amdgcn_exp2f(v0[jj] - m0);
          s1 += __builtin_amdgcn_exp2f(v1[jj] - m1);
          s2 += __builtin_amdgcn_exp2f(v2[jj] - m2);
          s3 += __builtin_amdgcn_exp2f(v3[jj] - m3);
        }
#pragma unroll
        for (int off = 32; off >= 1; off >>= 1) {
          s0 += __shfl_xor(s0, off, 64);
          s1 += __shfl_xor(s1, off, 64);
          s2 += __shfl_xor(s2, off, 64);
          s3 += __shfl_xor(s3, off, 64);
        }
        if (lane == 0) {
          float o0 = fmaf(c1, rc0 + m0 + __builtin_amdgcn_logf(s0), c2);
          float o1 = fmaf(c1, rc1 + m1 + __builtin_amdgcn_logf(s1), c2);
          float o2 = fmaf(c1, rc2 + m2 + __builtin_amdgcn_logf(s2), c2);
          float o3 = fmaf(c1, rc3 + m3 + __builtin_amdgcn_logf(s3), c2);
          __hip_atomic_store(&pout[r0],   o0, __ATOMIC_RELAXED, __HIP_MEMORY_SCOPE_AGENT);
          __hip_atomic_store(&pout[r0+1], o1, __ATOMIC_RELAXED, __HIP_MEMORY_SCOPE_AGENT);
          __hip_atomic_store(&pout[r0+2], o2, __ATOMIC_RELAXED, __HIP_MEMORY_SCOPE_AGENT);
          __hip_atomic_store(&pout[r0+3], o3, __ATOMIC_RELAXED, __HIP_MEMORY_SCOPE_AGENT);
        }
      }
      ++epoch;
      batch_barrier(cnt, gen, epoch);
    }
  }
}

// ---------------- fused argmin(sqdist - g) + gather + interp + MLP ----------------
__global__ __launch_bounds__(256) void assign_mlp_kernel(
    const float4* __restrict__ np4, const float4* __restrict__ x0p,
    const float* __restrict__ g, const float* __restrict__ t,
    const float* __restrict__ W1, const float* __restrict__ Wt,
    const float* __restrict__ b1, const float* __restrict__ W2,
    const float* __restrict__ b2, float* __restrict__ out) {
  __shared__ float4 sPts[N_];                 // x0 points
  __shared__ float  sg[N_];
  __shared__ float  sW1[3*H_], sWt[H_], sb1[H_], sW2[H_*3], sb2[3];
  int tid = threadIdx.x;
  int b = blockIdx.x >> 8;
  int rowBase = (blockIdx.x & 255) << 3;
  int base = b * N_;
  for (int j = tid; j < N_; j += 256) { sPts[j] = x0p[base+j]; sg[j] = g[base+j]; }
  for (int i = tid; i < 3*H_; i += 256) { sW1[i] = W1[i]; sW2[i] = W2[i]; }
  if (tid < H_) { sWt[tid] = Wt[tid]; sb1[tid] = b1[tid]; }
  if (tid < 3) sb2[tid] = b2[tid];
  __syncthreads();
  int wave = tid >> 6, lane = tid & 63;
  float tb = t[b];
  for (int rr = 0; rr < 2; ++rr) {
    int r = rowBase + (wave << 1) + rr;
    float4 A = np4[base + r];
    float best = INFINITY; int bidx = 0;
#pragma unroll
    for (int jj = 0; jj < 32; ++jj) {
      int j = (jj << 6) + lane;
      float4 p = sPts[j];
      float d = A.x*p.x + A.y*p.y + A.z*p.z;
      float val = fmaxf(A.w + p.w - 2.0f*d, 0.0f) - sg[j];
      if (val < best) { best = val; bidx = j; }   // strict < keeps lowest j per lane
    }
#pragma unroll
    for (int off = 32; off >= 1; off >>= 1) {
      float ov = __shfl_xor(best, off, 64);
      int   oi = __shfl_xor(bidx, off, 64);
      if (ov < best || (ov == best && oi < bidx)) { best = ov; bidx = oi; }
    }
    float4 xa = sPts[bidx];
    float xtx = (1.0f - tb)*xa.x + tb*A.x;
    float xty = (1.0f - tb)*xa.y + tb*A.y;
    float xtz = (1.0f - tb)*xa.z + tb*A.z;
    float acc0 = 0.f, acc1 = 0.f, acc2 = 0.f;
#pragma unroll
    for (int hh = 0; hh < 4; ++hh) {
      int h = (hh << 6) + lane;
      float hv = xtx*sW1[h] + xty*sW1[H_+h] + xtz*sW1[2*H_+h] + tb*sWt[h] + sb1[h];
      hv = fmaxf(hv, 0.0f);
      acc0 += hv * sW2[3*h];
      acc1 += hv * sW2[3*h+1];
      acc2 += hv * sW2[3*h+2];
    }
#pragma unroll
    for (int off = 32; off >= 1; off >>= 1) {
      acc0 += __shfl_xor(acc0, off, 64);
      acc1 += __shfl_xor(acc1, off, 64);
      acc2 += __shfl_xor(acc2, off, 64);
    }
    if (lane == 0) {
      int gi = base + r;
      out[3*gi]   = acc0 + sb2[0];
      out[3*gi+1] = acc1 + sb2[1];
      out[3*gi+2] = acc2 + sb2[2];
      out[3*BN_ + 3*gi]   = A.x - xa.x;
      out[3*BN_ + 3*gi+1] = A.y - xa.y;
      out[3*BN_ + 3*gi+2] = A.z - xa.z;
    }
  }
}

extern "C" void kernel_launch(void* const* d_in, const int* in_sizes, int n_in,
                              void* d_out, int out_size, void* d_ws, size_t ws_size,
                              hipStream_t stream) {
  (void)in_sizes; (void)n_in; (void)out_size; (void)ws_size;
  const float* cloud = (const float*)d_in[0];
  const float* noise = (const float*)d_in[1];
  const float* t     = (const float*)d_in[2];
  const float* W1    = (const float*)d_in[3];
  const float* Wt    = (const float*)d_in[4];
  const float* b1    = (const float*)d_in[5];
  const float* W2    = (const float*)d_in[6];
  const float* b2w   = (const float*)d_in[7];
  float* out = (float*)d_out;

  float* ws   = (float*)d_ws;
  float* stdv = ws;                         // 8 floats (pad to 16)
  float4* x0p = (float4*)(ws + 16);         // BN_ float4
  float4* np4 = (float4*)(ws + 16 + 4*BN_); // BN_ float4
  float* f    = ws + 16 + 8*BN_;            // BN_
  float* g    = f + BN_;                    // BN_

  std_kernel<<<B_, 256, 0, stream>>>(cloud, stdv);
  prep_kernel<<<BN_/256, 256, 0, stream>>>(cloud, noise, stdv, x0p, np4, f, g);

  const double LOG2E = 1.4426950408889634074;
  const double LN2   = 0.6931471805599453094;
  const double logw  = -log(2048.0);          // loga == logb == -log(N)
  const double l0 = log10(32.0), l1 = log10(1e-6);
  EpsTab tab;
  for (int kit = 0; kit < NITER_; ++kit) {
    // np.geomspace(32, 1e-6, 14) == 10**linspace(log10(32), -6, 14), cast fp32
    double epsd = pow(10.0, l0 + (l1 - l0) * ((double)kit / 13.0));
    float eps = (float)epsd;
    tab.kk[kit]  = (float)(LOG2E / (double)eps);
    tab.hh[kit]  = 0.5f * tab.kk[kit];
    tab.scl[kit] = sqrtf(tab.kk[kit]);
    tab.c1[kit]  = (float)(-(double)eps * LN2);
    tab.c2[kit]  = (float)(-(double)eps * logw);
  }

  sinkhorn_kernel<<<256, 256, 0, stream>>>(x0p, np4, f, g, tab);

  assign_mlp_kernel<<<B_*(N_/8), 256, 0, stream>>>(np4, x0p, g, t, W1, Wt, b1, W2, b2w, out);
}

// Round 6
// 970.635 us; speedup vs baseline: 1.0806x; 1.0806x over previous
//
#include <hip/hip_runtime.h>
#include <math.h>

#define B_ 8
#define N_ 2048
#define D_ 3
#define H_ 256
#define ND_ (N_*D_)     // 6144
#define BN_ (B_*N_)     // 16384
#define NITER_ 14

typedef __attribute__((ext_vector_type(2))) float v2f;

struct EpsTab { float scl[NITER_], kk[NITER_], hh[NITER_], c1[NITER_], c2[NITER_]; };

// barrier state in a device global: immune to ws_size, zeroed by prep each call
__device__ unsigned g_bar[256];

__device__ inline v2f exp2v(v2f a) {
  return (v2f){__builtin_amdgcn_exp2f(a.x), __builtin_amdgcn_exp2f(a.y)};
}

// ---------------- per-batch std (ddof=1) ----------------
__global__ __launch_bounds__(256) void std_kernel(const float* __restrict__ cloud,
                                                  float* __restrict__ stdv) {
  __shared__ float red[256];
  int b = blockIdx.x, tid = threadIdx.x;
  const float* p = cloud + (size_t)b * ND_;
  float s = 0.f;
  for (int i = tid; i < ND_; i += 256) s += p[i];
  red[tid] = s; __syncthreads();
  for (int off = 128; off > 0; off >>= 1) {
    if (tid < off) red[tid] += red[tid + off];
    __syncthreads();
  }
  float mean = red[0] / (float)ND_;
  __syncthreads();
  float ss = 0.f;
  for (int i = tid; i < ND_; i += 256) { float d = p[i] - mean; ss += d * d; }
  red[tid] = ss; __syncthreads();
  for (int off = 128; off > 0; off >>= 1) {
    if (tid < off) red[tid] += red[tid + off];
    __syncthreads();
  }
  if (tid == 0) stdv[b] = sqrtf(red[0] / (float)(ND_ - 1));
}

// ------- pack points as (x,y,z,|p|^2), zero potentials + barrier state -------
__global__ __launch_bounds__(256) void prep_kernel(const float* __restrict__ cloud,
    const float* __restrict__ noise, const float* __restrict__ stdv,
    float4* __restrict__ x0p, float4* __restrict__ np4,
    float* __restrict__ f, float* __restrict__ g) {
  int i = blockIdx.x * 256 + threadIdx.x;
  if (blockIdx.x == 0)
    __hip_atomic_store(&g_bar[threadIdx.x], 0u, __ATOMIC_RELAXED, __HIP_MEMORY_SCOPE_AGENT);
  if (i >= BN_) return;
  int b = i >> 11;
  float sd = stdv[b];
  float cx = cloud[3*i] / sd, cy = cloud[3*i+1] / sd, cz = cloud[3*i+2] / sd;
  x0p[i] = make_float4(cx, cy, cz, cx*cx + cy*cy + cz*cz);
  float ax = noise[3*i], ay = noise[3*i+1], az = noise[3*i+2];
  np4[i] = make_float4(ax, ay, az, ax*ax + ay*ay + az*az);
  f[i] = 0.f; g[i] = 0.f;
}

// per-batch epoch barrier: 64 participating blocks, agent-scope atomics.
// RELAXED polls (no per-poll cache invalidate); fences only at entry/exit.
__device__ inline void batch_barrier(unsigned* cnt, unsigned* gen, unsigned epoch) {
  __syncthreads();
  if (threadIdx.x == 0) {
    __threadfence();
    unsigned old = __hip_atomic_fetch_add(cnt, 1u, __ATOMIC_ACQ_REL, __HIP_MEMORY_SCOPE_AGENT);
    if (old == 63u) {
      __hip_atomic_store(cnt, 0u, __ATOMIC_RELAXED, __HIP_MEMORY_SCOPE_AGENT);
      __hip_atomic_fetch_add(gen, 1u, __ATOMIC_ACQ_REL, __HIP_MEMORY_SCOPE_AGENT);
    } else {
      while (__hip_atomic_load(gen, __ATOMIC_RELAXED, __HIP_MEMORY_SCOPE_AGENT) < epoch) {
        __builtin_amdgcn_s_sleep(2);
      }
    }
    __threadfence();
  }
  __syncthreads();
}

// ---------------- all 28 Sinkhorn half-iterations in one launch ----------------
// 512 blocks x 256 thr, 2 blocks/CU co-resident (capacity >=4 by VGPR/LDS).
// batch = blockIdx & 7 -> co-located blocks usually belong to DIFFERENT batches,
// so one batch's barrier wait overlaps the other's compute.
// Each block: 32 rows (2 grps x 4 waves x 4 rows). Rows packed in float2 pairs
// (v_pk_fma_f32 / v_pk_max_f32); lse chunked (2x16 j) with (M,S) merge to keep
// register arrays at 64 VGPRs (round-5's 128-float arrays forced recompute @80 VGPR).
__global__ __launch_bounds__(256, 2) void sinkhorn_kernel(
    const float4* __restrict__ x0p, const float4* __restrict__ np4,
    float* f, float* g, EpsTab tab) {
  __shared__ float4 sP[N_];   // 32 KB: scaled coords + q
  int tid = threadIdx.x;
  int b   = blockIdx.x & 7;            // interleaved batches
  int blk = blockIdx.x >> 3;           // 64 blocks/batch, 32 rows/block
  int base = b * N_;
  unsigned* cnt = &g_bar[b * 16];
  unsigned* gen = &g_bar[128 + b * 16];
  int wave = tid >> 6, lane = tid & 63;
  unsigned epoch = 0;
  for (int kit = 0; kit < NITER_; ++kit) {
    float scl = tab.scl[kit], kk = tab.kk[kit], hh = tab.hh[kit];
    float c1 = tab.c1[kit], c2 = tab.c2[kit];
    for (int half = 0; half < 2; ++half) {
      const float4* outer = half ? x0p : np4;
      const float4* inner = half ? np4 : x0p;
      float*        pin   = half ? f : g;
      float*        pout  = half ? g : f;
      for (int j = tid; j < N_; j += 256) {
        float4 p = inner[base + j];
        float pot = __hip_atomic_load(&pin[base + j], __ATOMIC_RELAXED, __HIP_MEMORY_SCOPE_AGENT);
        float q = fmaf(kk, pot, -hh * p.w);
        sP[j] = make_float4(scl * p.x, scl * p.y, scl * p.z, q);
      }
      __syncthreads();
      for (int grp = 0; grp < 2; ++grp) {
        int r0 = base + (blk << 5) + (grp << 4) + (wave << 2);
        float4 A0 = outer[r0], A1 = outer[r0+1], A2 = outer[r0+2], A3 = outer[r0+3];
        v2f a01x = {scl*A0.x, scl*A1.x}, a23x = {scl*A2.x, scl*A3.x};
        v2f a01y = {scl*A0.y, scl*A1.y}, a23y = {scl*A2.y, scl*A3.y};
        v2f a01z = {scl*A0.z, scl*A1.z}, a23z = {scl*A2.z, scl*A3.z};
        v2f rc01 = {-hh*A0.w, -hh*A1.w}, rc23 = {-hh*A2.w, -hh*A3.w};
        v2f M01 = {-INFINITY, -INFINITY}, M23 = {-INFINITY, -INFINITY};
        v2f S01 = {0.f, 0.f}, S23 = {0.f, 0.f};
#pragma unroll
        for (int c = 0; c < 2; ++c) {
          v2f v01[16], v23[16];
          v2f m01 = {-INFINITY, -INFINITY}, m23 = {-INFINITY, -INFINITY};
#pragma unroll
          for (int jj = 0; jj < 16; ++jj) {
            float4 p = sP[(((c << 4) + jj) << 6) + lane];
            v2f px = {p.x, p.x}, py = {p.y, p.y}, pz = {p.z, p.z}, pw = {p.w, p.w};
            v2f t01 = __builtin_elementwise_fma(px, a01x, pw);
            t01 = __builtin_elementwise_fma(py, a01y, t01);
            t01 = __builtin_elementwise_fma(pz, a01z, t01);
            v01[jj] = t01; m01 = __builtin_elementwise_max(m01, t01);
            v2f t23 = __builtin_elementwise_fma(px, a23x, pw);
            t23 = __builtin_elementwise_fma(py, a23y, t23);
            t23 = __builtin_elementwise_fma(pz, a23z, t23);
            v23[jj] = t23; m23 = __builtin_elementwise_max(m23, t23);
          }
          v2f s01 = {0.f, 0.f}, s23 = {0.f, 0.f};
#pragma unroll
          for (int jj = 0; jj < 16; ++jj) {
            s01 += exp2v(v01[jj] - m01);
            s23 += exp2v(v23[jj] - m23);
          }
          // merge chunk (m,s) into running (M,S)
          v2f nm01 = __builtin_elementwise_max(M01, m01);
          S01 = S01 * exp2v(M01 - nm01) + s01 * exp2v(m01 - nm01);
          M01 = nm01;
          v2f nm23 = __builtin_elementwise_max(M23, m23);
          S23 = S23 * exp2v(M23 - nm23) + s23 * exp2v(m23 - nm23);
          M23 = nm23;
        }
        // wave-level reduction: global max, rescale, sum
        v2f Mg01 = M01, Mg23 = M23;
#pragma unroll
        for (int off = 32; off >= 1; off >>= 1) {
          v2f o01 = {__shfl_xor(Mg01.x, off, 64), __shfl_xor(Mg01.y, off, 64)};
          v2f o23 = {__shfl_xor(Mg23.x, off, 64), __shfl_xor(Mg23.y, off, 64)};
          Mg01 = __builtin_elementwise_max(Mg01, o01);
          Mg23 = __builtin_elementwise_max(Mg23, o23);
        }
        S01 *= exp2v(M01 - Mg01);
        S23 *= exp2v(M23 - Mg23);
#pragma unroll
        for (int off = 32; off >= 1; off >>= 1) {
          S01 += (v2f){__shfl_xor(S01.x, off, 64), __shfl_xor(S01.y, off, 64)};
          S23 += (v2f){__shfl_xor(S23.x, off, 64), __shfl_xor(S23.y, off, 64)};
        }
        if (lane == 0) {
          float o0 = fmaf(c1, rc01.x + Mg01.x + __builtin_amdgcn_logf(S01.x), c2);
          float o1 = fmaf(c1, rc01.y + Mg01.y + __builtin_amdgcn_logf(S01.y), c2);
          float o2 = fmaf(c1, rc23.x + Mg23.x + __builtin_amdgcn_logf(S23.x), c2);
          float o3 = fmaf(c1, rc23.y + Mg23.y + __builtin_amdgcn_logf(S23.y), c2);
          __hip_atomic_store(&pout[r0],   o0, __ATOMIC_RELAXED, __HIP_MEMORY_SCOPE_AGENT);
          __hip_atomic_store(&pout[r0+1], o1, __ATOMIC_RELAXED, __HIP_MEMORY_SCOPE_AGENT);
          __hip_atomic_store(&pout[r0+2], o2, __ATOMIC_RELAXED, __HIP_MEMORY_SCOPE_AGENT);
          __hip_atomic_store(&pout[r0+3], o3, __ATOMIC_RELAXED, __HIP_MEMORY_SCOPE_AGENT);
        }
      }
      ++epoch;
      batch_barrier(cnt, gen, epoch);
    }
  }
}

// ---------------- fused argmin(sqdist - g) + gather + interp + MLP ----------------
__global__ __launch_bounds__(256) void assign_mlp_kernel(
    const float4* __restrict__ np4, const float4* __restrict__ x0p,
    const float* __restrict__ g, const float* __restrict__ t,
    const float* __restrict__ W1, const float* __restrict__ Wt,
    const float* __restrict__ b1, const float* __restrict__ W2,
    const float* __restrict__ b2, float* __restrict__ out) {
  __shared__ float4 sPts[N_];                 // x0 points
  __shared__ float  sg[N_];
  __shared__ float  sW1[3*H_], sWt[H_], sb1[H_], sW2[H_*3], sb2[3];
  int tid = threadIdx.x;
  int b = blockIdx.x >> 8;
  int rowBase = (blockIdx.x & 255) << 3;
  int base = b * N_;
  for (int j = tid; j < N_; j += 256) { sPts[j] = x0p[base+j]; sg[j] = g[base+j]; }
  for (int i = tid; i < 3*H_; i += 256) { sW1[i] = W1[i]; sW2[i] = W2[i]; }
  if (tid < H_) { sWt[tid] = Wt[tid]; sb1[tid] = b1[tid]; }
  if (tid < 3) sb2[tid] = b2[tid];
  __syncthreads();
  int wave = tid >> 6, lane = tid & 63;
  float tb = t[b];
  for (int rr = 0; rr < 2; ++rr) {
    int r = rowBase + (wave << 1) + rr;
    float4 A = np4[base + r];
    float best = INFINITY; int bidx = 0;
#pragma unroll
    for (int jj = 0; jj < 32; ++jj) {
      int j = (jj << 6) + lane;
      float4 p = sPts[j];
      float d = A.x*p.x + A.y*p.y + A.z*p.z;
      float val = fmaxf(A.w + p.w - 2.0f*d, 0.0f) - sg[j];
      if (val < best) { best = val; bidx = j; }   // strict < keeps lowest j per lane
    }
#pragma unroll
    for (int off = 32; off >= 1; off >>= 1) {
      float ov = __shfl_xor(best, off, 64);
      int   oi = __shfl_xor(bidx, off, 64);
      if (ov < best || (ov == best && oi < bidx)) { best = ov; bidx = oi; }
    }
    float4 xa = sPts[bidx];
    float xtx = (1.0f - tb)*xa.x + tb*A.x;
    float xty = (1.0f - tb)*xa.y + tb*A.y;
    float xtz = (1.0f - tb)*xa.z + tb*A.z;
    float acc0 = 0.f, acc1 = 0.f, acc2 = 0.f;
#pragma unroll
    for (int hh = 0; hh < 4; ++hh) {
      int h = (hh << 6) + lane;
      float hv = xtx*sW1[h] + xty*sW1[H_+h] + xtz*sW1[2*H_+h] + tb*sWt[h] + sb1[h];
      hv = fmaxf(hv, 0.0f);
      acc0 += hv * sW2[3*h];
      acc1 += hv * sW2[3*h+1];
      acc2 += hv * sW2[3*h+2];
    }
#pragma unroll
    for (int off = 32; off >= 1; off >>= 1) {
      acc0 += __shfl_xor(acc0, off, 64);
      acc1 += __shfl_xor(acc1, off, 64);
      acc2 += __shfl_xor(acc2, off, 64);
    }
    if (lane == 0) {
      int gi = base + r;
      out[3*gi]   = acc0 + sb2[0];
      out[3*gi+1] = acc1 + sb2[1];
      out[3*gi+2] = acc2 + sb2[2];
      out[3*BN_ + 3*gi]   = A.x - xa.x;
      out[3*BN_ + 3*gi+1] = A.y - xa.y;
      out[3*BN_ + 3*gi+2] = A.z - xa.z;
    }
  }
}

extern "C" void kernel_launch(void* const* d_in, const int* in_sizes, int n_in,
                              void* d_out, int out_size, void* d_ws, size_t ws_size,
                              hipStream_t stream) {
  (void)in_sizes; (void)n_in; (void)out_size; (void)ws_size;
  const float* cloud = (const float*)d_in[0];
  const float* noise = (const float*)d_in[1];
  const float* t     = (const float*)d_in[2];
  const float* W1    = (const float*)d_in[3];
  const float* Wt    = (const float*)d_in[4];
  const float* b1    = (const float*)d_in[5];
  const float* W2    = (const float*)d_in[6];
  const float* b2w   = (const float*)d_in[7];
  float* out = (float*)d_out;

  float* ws   = (float*)d_ws;
  float* stdv = ws;                         // 8 floats (pad to 16)
  float4* x0p = (float4*)(ws + 16);         // BN_ float4
  float4* np4 = (float4*)(ws + 16 + 4*BN_); // BN_ float4
  float* f    = ws + 16 + 8*BN_;            // BN_
  float* g    = f + BN_;                    // BN_

  std_kernel<<<B_, 256, 0, stream>>>(cloud, stdv);
  prep_kernel<<<BN_/256, 256, 0, stream>>>(cloud, noise, stdv, x0p, np4, f, g);

  const double LOG2E = 1.4426950408889634074;
  const double LN2   = 0.6931471805599453094;
  const double logw  = -log(2048.0);          // loga == logb == -log(N)
  const double l0 = log10(32.0), l1 = log10(1e-6);
  EpsTab tab;
  for (int kit = 0; kit < NITER_; ++kit) {
    // np.geomspace(32, 1e-6, 14) == 10**linspace(log10(32), -6, 14), cast fp32
    double epsd = pow(10.0, l0 + (l1 - l0) * ((double)kit / 13.0));
    float eps = (float)epsd;
    tab.kk[kit]  = (float)(LOG2E / (double)eps);
    tab.hh[kit]  = 0.5f * tab.kk[kit];
    tab.scl[kit] = sqrtf(tab.kk[kit]);
    tab.c1[kit]  = (float)(-(double)eps * LN2);
    tab.c2[kit]  = (float)(-(double)eps * logw);
  }

  sinkhorn_kernel<<<512, 256, 0, stream>>>(x0p, np4, f, g, tab);

  assign_mlp_kernel<<<B_*(N_/8), 256, 0, stream>>>(np4, x0p, g, t, W1, Wt, b1, W2, b2w, out);
}

// Round 7
// 445.563 us; speedup vs baseline: 2.3541x; 2.1784x over previous
//
#include <hip/hip_runtime.h>
#include <math.h>

#define B_ 8
#define N_ 2048
#define D_ 3
#define H_ 256
#define ND_ (N_*D_)     // 6144
#define BN_ (B_*N_)     // 16384
#define NITER_ 14

typedef __attribute__((ext_vector_type(2))) float v2f;

struct EpsTab { float scl[NITER_], kk[NITER_], hh[NITER_], c1[NITER_], c2[NITER_]; };

// barrier state in a device global: immune to ws_size, zeroed by prep each call
__device__ unsigned g_bar[256];

__device__ inline v2f exp2v(v2f a) {
  return (v2f){__builtin_amdgcn_exp2f(a.x), __builtin_amdgcn_exp2f(a.y)};
}

// ---------------- per-batch std (ddof=1) ----------------
__global__ __launch_bounds__(256) void std_kernel(const float* __restrict__ cloud,
                                                  float* __restrict__ stdv) {
  __shared__ float red[256];
  int b = blockIdx.x, tid = threadIdx.x;
  const float* p = cloud + (size_t)b * ND_;
  float s = 0.f;
  for (int i = tid; i < ND_; i += 256) s += p[i];
  red[tid] = s; __syncthreads();
  for (int off = 128; off > 0; off >>= 1) {
    if (tid < off) red[tid] += red[tid + off];
    __syncthreads();
  }
  float mean = red[0] / (float)ND_;
  __syncthreads();
  float ss = 0.f;
  for (int i = tid; i < ND_; i += 256) { float d = p[i] - mean; ss += d * d; }
  red[tid] = ss; __syncthreads();
  for (int off = 128; off > 0; off >>= 1) {
    if (tid < off) red[tid] += red[tid + off];
    __syncthreads();
  }
  if (tid == 0) stdv[b] = sqrtf(red[0] / (float)(ND_ - 1));
}

// ------- pack points as (x,y,z,|p|^2), zero potentials + barrier state -------
__global__ __launch_bounds__(256) void prep_kernel(const float* __restrict__ cloud,
    const float* __restrict__ noise, const float* __restrict__ stdv,
    float4* __restrict__ x0p, float4* __restrict__ np4,
    float* __restrict__ f, float* __restrict__ g) {
  int i = blockIdx.x * 256 + threadIdx.x;
  if (blockIdx.x == 0)
    __hip_atomic_store(&g_bar[threadIdx.x], 0u, __ATOMIC_RELAXED, __HIP_MEMORY_SCOPE_AGENT);
  if (i >= BN_) return;
  int b = i >> 11;
  float sd = stdv[b];
  float cx = cloud[3*i] / sd, cy = cloud[3*i+1] / sd, cz = cloud[3*i+2] / sd;
  x0p[i] = make_float4(cx, cy, cz, cx*cx + cy*cy + cz*cz);
  float ax = noise[3*i], ay = noise[3*i+1], az = noise[3*i+2];
  np4[i] = make_float4(ax, ay, az, ax*ax + ay*ay + az*az);
  f[i] = 0.f; g[i] = 0.f;
}

// per-batch epoch barrier: 64 participating blocks, FENCE-FREE.
// All pout stores / pin loads are agent-scope relaxed atomics -> sc1 flag ->
// bypass the non-coherent per-XCD L2 and are coherent at the LLC. HIP's
// __syncthreads() drains vmcnt(0) before s_barrier, so every wave's pout
// stores have reached the LLC before tid0 increments cnt. No __threadfence
// (whose buffer_wbl2/buffer_inv L2-flush storm caused round 6's 1.27 GB
// HBM refetch per dispatch and ~26 us/half-sweep of stall).
__device__ inline void batch_barrier(unsigned* cnt, unsigned* gen, unsigned epoch) {
  __syncthreads();   // compiler emits s_waitcnt vmcnt(0) before s_barrier
  if (threadIdx.x == 0) {
    unsigned old = __hip_atomic_fetch_add(cnt, 1u, __ATOMIC_RELAXED, __HIP_MEMORY_SCOPE_AGENT);
    if (old == 63u) {
      __hip_atomic_store(cnt, 0u, __ATOMIC_RELAXED, __HIP_MEMORY_SCOPE_AGENT);
      asm volatile("s_waitcnt vmcnt(0)" ::: "memory");  // cnt reset at LLC before gen bump
      __hip_atomic_store(gen, epoch, __ATOMIC_RELAXED, __HIP_MEMORY_SCOPE_AGENT);
    } else {
      while (__hip_atomic_load(gen, __ATOMIC_RELAXED, __HIP_MEMORY_SCOPE_AGENT) < epoch) {
        __builtin_amdgcn_s_sleep(1);
      }
    }
  }
  __syncthreads();
}

// ---------------- all 28 Sinkhorn half-iterations in one launch ----------------
// 512 blocks x 256 thr, 2 blocks/CU co-resident; batch = blockIdx & 7 so
// co-located blocks usually belong to DIFFERENT batches (barrier wait of one
// overlaps compute of the other). Each block: 32 rows (2 grps x 4 waves x 4
// rows), rows packed in float2 pairs (v_pk_fma_f32/v_pk_max_f32), lse chunked
// (2x16 j) with (M,S) merge. Identical compute to round 6 — only the barrier
// changed this round.
__global__ __launch_bounds__(256, 2) void sinkhorn_kernel(
    const float4* __restrict__ x0p, const float4* __restrict__ np4,
    float* f, float* g, EpsTab tab) {
  __shared__ float4 sP[N_];   // 32 KB: scaled coords + q
  int tid = threadIdx.x;
  int b   = blockIdx.x & 7;            // interleaved batches
  int blk = blockIdx.x >> 3;           // 64 blocks/batch, 32 rows/block
  int base = b * N_;
  unsigned* cnt = &g_bar[b * 16];
  unsigned* gen = &g_bar[128 + b * 16];
  int wave = tid >> 6, lane = tid & 63;
  unsigned epoch = 0;
  for (int kit = 0; kit < NITER_; ++kit) {
    float scl = tab.scl[kit], kk = tab.kk[kit], hh = tab.hh[kit];
    float c1 = tab.c1[kit], c2 = tab.c2[kit];
    for (int half = 0; half < 2; ++half) {
      const float4* outer = half ? x0p : np4;
      const float4* inner = half ? np4 : x0p;
      float*        pin   = half ? f : g;
      float*        pout  = half ? g : f;
      for (int j = tid; j < N_; j += 256) {
        float4 p = inner[base + j];
        float pot = __hip_atomic_load(&pin[base + j], __ATOMIC_RELAXED, __HIP_MEMORY_SCOPE_AGENT);
        float q = fmaf(kk, pot, -hh * p.w);
        sP[j] = make_float4(scl * p.x, scl * p.y, scl * p.z, q);
      }
      __syncthreads();
      for (int grp = 0; grp < 2; ++grp) {
        int r0 = base + (blk << 5) + (grp << 4) + (wave << 2);
        float4 A0 = outer[r0], A1 = outer[r0+1], A2 = outer[r0+2], A3 = outer[r0+3];
        v2f a01x = {scl*A0.x, scl*A1.x}, a23x = {scl*A2.x, scl*A3.x};
        v2f a01y = {scl*A0.y, scl*A1.y}, a23y = {scl*A2.y, scl*A3.y};
        v2f a01z = {scl*A0.z, scl*A1.z}, a23z = {scl*A2.z, scl*A3.z};
        v2f rc01 = {-hh*A0.w, -hh*A1.w}, rc23 = {-hh*A2.w, -hh*A3.w};
        v2f M01 = {-INFINITY, -INFINITY}, M23 = {-INFINITY, -INFINITY};
        v2f S01 = {0.f, 0.f}, S23 = {0.f, 0.f};
#pragma unroll
        for (int c = 0; c < 2; ++c) {
          v2f v01[16], v23[16];
          v2f m01 = {-INFINITY, -INFINITY}, m23 = {-INFINITY, -INFINITY};
#pragma unroll
          for (int jj = 0; jj < 16; ++jj) {
            float4 p = sP[(((c << 4) + jj) << 6) + lane];
            v2f px = {p.x, p.x}, py = {p.y, p.y}, pz = {p.z, p.z}, pw = {p.w, p.w};
            v2f t01 = __builtin_elementwise_fma(px, a01x, pw);
            t01 = __builtin_elementwise_fma(py, a01y, t01);
            t01 = __builtin_elementwise_fma(pz, a01z, t01);
            v01[jj] = t01; m01 = __builtin_elementwise_max(m01, t01);
            v2f t23 = __builtin_elementwise_fma(px, a23x, pw);
            t23 = __builtin_elementwise_fma(py, a23y, t23);
            t23 = __builtin_elementwise_fma(pz, a23z, t23);
            v23[jj] = t23; m23 = __builtin_elementwise_max(m23, t23);
          }
          v2f s01 = {0.f, 0.f}, s23 = {0.f, 0.f};
#pragma unroll
          for (int jj = 0; jj < 16; ++jj) {
            s01 += exp2v(v01[jj] - m01);
            s23 += exp2v(v23[jj] - m23);
          }
          // merge chunk (m,s) into running (M,S)
          v2f nm01 = __builtin_elementwise_max(M01, m01);
          S01 = S01 * exp2v(M01 - nm01) + s01 * exp2v(m01 - nm01);
          M01 = nm01;
          v2f nm23 = __builtin_elementwise_max(M23, m23);
          S23 = S23 * exp2v(M23 - nm23) + s23 * exp2v(m23 - nm23);
          M23 = nm23;
        }
        // wave-level reduction: global max, rescale, sum
        v2f Mg01 = M01, Mg23 = M23;
#pragma unroll
        for (int off = 32; off >= 1; off >>= 1) {
          v2f o01 = {__shfl_xor(Mg01.x, off, 64), __shfl_xor(Mg01.y, off, 64)};
          v2f o23 = {__shfl_xor(Mg23.x, off, 64), __shfl_xor(Mg23.y, off, 64)};
          Mg01 = __builtin_elementwise_max(Mg01, o01);
          Mg23 = __builtin_elementwise_max(Mg23, o23);
        }
        S01 *= exp2v(M01 - Mg01);
        S23 *= exp2v(M23 - Mg23);
#pragma unroll
        for (int off = 32; off >= 1; off >>= 1) {
          S01 += (v2f){__shfl_xor(S01.x, off, 64), __shfl_xor(S01.y, off, 64)};
          S23 += (v2f){__shfl_xor(S23.x, off, 64), __shfl_xor(S23.y, off, 64)};
        }
        if (lane == 0) {
          float o0 = fmaf(c1, rc01.x + Mg01.x + __builtin_amdgcn_logf(S01.x), c2);
          float o1 = fmaf(c1, rc01.y + Mg01.y + __builtin_amdgcn_logf(S01.y), c2);
          float o2 = fmaf(c1, rc23.x + Mg23.x + __builtin_amdgcn_logf(S23.x), c2);
          float o3 = fmaf(c1, rc23.y + Mg23.y + __builtin_amdgcn_logf(S23.y), c2);
          __hip_atomic_store(&pout[r0],   o0, __ATOMIC_RELAXED, __HIP_MEMORY_SCOPE_AGENT);
          __hip_atomic_store(&pout[r0+1], o1, __ATOMIC_RELAXED, __HIP_MEMORY_SCOPE_AGENT);
          __hip_atomic_store(&pout[r0+2], o2, __ATOMIC_RELAXED, __HIP_MEMORY_SCOPE_AGENT);
          __hip_atomic_store(&pout[r0+3], o3, __ATOMIC_RELAXED, __HIP_MEMORY_SCOPE_AGENT);
        }
      }
      ++epoch;
      batch_barrier(cnt, gen, epoch);
    }
  }
}

// ---------------- fused argmin(sqdist - g) + gather + interp + MLP ----------------
__global__ __launch_bounds__(256) void assign_mlp_kernel(
    const float4* __restrict__ np4, const float4* __restrict__ x0p,
    const float* __restrict__ g, const float* __restrict__ t,
    const float* __restrict__ W1, const float* __restrict__ Wt,
    const float* __restrict__ b1, const float* __restrict__ W2,
    const float* __restrict__ b2, float* __restrict__ out) {
  __shared__ float4 sPts[N_];                 // x0 points
  __shared__ float  sg[N_];
  __shared__ float  sW1[3*H_], sWt[H_], sb1[H_], sW2[H_*3], sb2[3];
  int tid = threadIdx.x;
  int b = blockIdx.x >> 8;
  int rowBase = (blockIdx.x & 255) << 3;
  int base = b * N_;
  for (int j = tid; j < N_; j += 256) { sPts[j] = x0p[base+j]; sg[j] = g[base+j]; }
  for (int i = tid; i < 3*H_; i += 256) { sW1[i] = W1[i]; sW2[i] = W2[i]; }
  if (tid < H_) { sWt[tid] = Wt[tid]; sb1[tid] = b1[tid]; }
  if (tid < 3) sb2[tid] = b2[tid];
  __syncthreads();
  int wave = tid >> 6, lane = tid & 63;
  float tb = t[b];
  for (int rr = 0; rr < 2; ++rr) {
    int r = rowBase + (wave << 1) + rr;
    float4 A = np4[base + r];
    float best = INFINITY; int bidx = 0;
#pragma unroll
    for (int jj = 0; jj < 32; ++jj) {
      int j = (jj << 6) + lane;
      float4 p = sPts[j];
      float d = A.x*p.x + A.y*p.y + A.z*p.z;
      float val = fmaxf(A.w + p.w - 2.0f*d, 0.0f) - sg[j];
      if (val < best) { best = val; bidx = j; }   // strict < keeps lowest j per lane
    }
#pragma unroll
    for (int off = 32; off >= 1; off >>= 1) {
      float ov = __shfl_xor(best, off, 64);
      int   oi = __shfl_xor(bidx, off, 64);
      if (ov < best || (ov == best && oi < bidx)) { best = ov; bidx = oi; }
    }
    float4 xa = sPts[bidx];
    float xtx = (1.0f - tb)*xa.x + tb*A.x;
    float xty = (1.0f - tb)*xa.y + tb*A.y;
    float xtz = (1.0f - tb)*xa.z + tb*A.z;
    float acc0 = 0.f, acc1 = 0.f, acc2 = 0.f;
#pragma unroll
    for (int hh = 0; hh < 4; ++hh) {
      int h = (hh << 6) + lane;
      float hv = xtx*sW1[h] + xty*sW1[H_+h] + xtz*sW1[2*H_+h] + tb*sWt[h] + sb1[h];
      hv = fmaxf(hv, 0.0f);
      acc0 += hv * sW2[3*h];
      acc1 += hv * sW2[3*h+1];
      acc2 += hv * sW2[3*h+2];
    }
#pragma unroll
    for (int off = 32; off >= 1; off >>= 1) {
      acc0 += __shfl_xor(acc0, off, 64);
      acc1 += __shfl_xor(acc1, off, 64);
      acc2 += __shfl_xor(acc2, off, 64);
    }
    if (lane == 0) {
      int gi = base + r;
      out[3*gi]   = acc0 + sb2[0];
      out[3*gi+1] = acc1 + sb2[1];
      out[3*gi+2] = acc2 + sb2[2];
      out[3*BN_ + 3*gi]   = A.x - xa.x;
      out[3*BN_ + 3*gi+1] = A.y - xa.y;
      out[3*BN_ + 3*gi+2] = A.z - xa.z;
    }
  }
}

extern "C" void kernel_launch(void* const* d_in, const int* in_sizes, int n_in,
                              void* d_out, int out_size, void* d_ws, size_t ws_size,
                              hipStream_t stream) {
  (void)in_sizes; (void)n_in; (void)out_size; (void)ws_size;
  const float* cloud = (const float*)d_in[0];
  const float* noise = (const float*)d_in[1];
  const float* t     = (const float*)d_in[2];
  const float* W1    = (const float*)d_in[3];
  const float* Wt    = (const float*)d_in[4];
  const float* b1    = (const float*)d_in[5];
  const float* W2    = (const float*)d_in[6];
  const float* b2w   = (const float*)d_in[7];
  float* out = (float*)d_out;

  float* ws   = (float*)d_ws;
  float* stdv = ws;                         // 8 floats (pad to 16)
  float4* x0p = (float4*)(ws + 16);         // BN_ float4
  float4* np4 = (float4*)(ws + 16 + 4*BN_); // BN_ float4
  float* f    = ws + 16 + 8*BN_;            // BN_
  float* g    = f + BN_;                    // BN_

  std_kernel<<<B_, 256, 0, stream>>>(cloud, stdv);
  prep_kernel<<<BN_/256, 256, 0, stream>>>(cloud, noise, stdv, x0p, np4, f, g);

  const double LOG2E = 1.4426950408889634074;
  const double LN2   = 0.6931471805599453094;
  const double logw  = -log(2048.0);          // loga == logb == -log(N)
  const double l0 = log10(32.0), l1 = log10(1e-6);
  EpsTab tab;
  for (int kit = 0; kit < NITER_; ++kit) {
    // np.geomspace(32, 1e-6, 14) == 10**linspace(log10(32), -6, 14), cast fp32
    double epsd = pow(10.0, l0 + (l1 - l0) * ((double)kit / 13.0));
    float eps = (float)epsd;
    tab.kk[kit]  = (float)(LOG2E / (double)eps);
    tab.hh[kit]  = 0.5f * tab.kk[kit];
    tab.scl[kit] = sqrtf(tab.kk[kit]);
    tab.c1[kit]  = (float)(-(double)eps * LN2);
    tab.c2[kit]  = (float)(-(double)eps * logw);
  }

  sinkhorn_kernel<<<512, 256, 0, stream>>>(x0p, np4, f, g, tab);

  assign_mlp_kernel<<<B_*(N_/8), 256, 0, stream>>>(np4, x0p, g, t, W1, Wt, b1, W2, b2w, out);
}